// Round 22
// baseline (154.193 us; speedup 1.0000x reference)
//
#include <hip/hip_runtime.h>
#include <hip/hip_bf16.h>

#define DM 512
#define HEADS 8
#define DEPTH 64
#define BATCH 4
#define SEQ 8192
#define MROWS (BATCH*SEQ)

using short8 = __attribute__((ext_vector_type(8))) short;
using floatx4 = __attribute__((ext_vector_type(4))) float;

#define AS1 __attribute__((address_space(1)))
#define AS3 __attribute__((address_space(3)))

static __device__ __forceinline__ float bf2f(unsigned short u) {
    union { unsigned int i; float f; } x; x.i = ((unsigned int)u) << 16; return x.f;
}
static __device__ __forceinline__ unsigned short f2bf(float f) {
    union { float f; unsigned int i; } x; x.f = f;
    unsigned int i = x.i;
    return (unsigned short)((i + 0x7FFFu + ((i >> 16) & 1u)) >> 16);
}
// RTZ pack: 3 VALU ops (A-staging only)
static __device__ __forceinline__ unsigned int pack2_rtz(float a, float b) {
    union { float f; unsigned int u; } x, y; x.f = a; y.f = b;
    return (x.u >> 16) | (y.u & 0xFFFF0000u);
}
static __device__ __forceinline__ void gl_lds16(const unsigned short* g, unsigned short* l) {
    __builtin_amdgcn_global_load_lds((const AS1 unsigned int*)g, (AS3 unsigned int*)l, 16, 0, 0);
}

// ---- W prep (merged): transpose + convert to bf16. wT[n][k] = w[k][n] ----
__global__ __launch_bounds__(256) void wprep_kernel(const float* __restrict__ wq,
                                                    const float* __restrict__ wk,
                                                    const float* __restrict__ wv,
                                                    unsigned short* __restrict__ wqT,
                                                    unsigned short* __restrict__ wkT,
                                                    unsigned short* __restrict__ wvT) {
    const float* w = blockIdx.y == 0 ? wq : (blockIdx.y == 1 ? wk : wv);
    unsigned short* wT = blockIdx.y == 0 ? wqT : (blockIdx.y == 1 ? wkT : wvT);
    int idx = blockIdx.x * 256 + threadIdx.x;
    int k = idx & (DM - 1);
    int n = idx >> 9;
    wT[n * DM + k] = f2bf(w[k * DM + n]);
}

// ---- Merged projection GEMM: Y = phi?(X @ W + bias), q/k/v in one dispatch ----
// R22 = R21 (best, 153.1us total) + s_setprio(1/0) around the MFMA clusters (T5).
// R21's mid-compute staging creates a stage-vs-MFMA role split within each
// iteration (one wave issuing STAGE_B/WRITE_A while the SIMD's other wave is in
// H1/H2 MFMA) — setprio lets the CU scheduler prefer the MFMA-issuing wave.
// Everything else bit-identical to R21 (9 variants bracket this as the optimum):
// BM=128/BN=512/BK=32, 8 waves, acc 4x8, chunk-XOR B, pad-40 A, LDS 84KB,
// counted-vmcnt(2) mid-stage pipeline, fences per rule 18.
__global__ __launch_bounds__(512) void proj3_kernel(
        const float* __restrict__ q, const float* __restrict__ k, const float* __restrict__ v,
        const unsigned short* __restrict__ wqT, const unsigned short* __restrict__ wkT,
        const unsigned short* __restrict__ wvT,
        const float* __restrict__ bq, const float* __restrict__ bk, const float* __restrict__ bv,
        unsigned short* __restrict__ qh, unsigned short* __restrict__ kh,
        unsigned short* __restrict__ vh) {
    __shared__ unsigned short As[2][128 * 40];   // 2 x 10 KiB (80B rows)
    __shared__ unsigned short Bs[2][512 * 32];   // 2 x 32 KiB (chunk-XOR contents)

    const int t = threadIdx.x;
    const int w = t >> 6;
    const int l15 = t & 15;
    const int g = (t >> 4) & 3;

    const int which = blockIdx.y;
    const float* X = which == 0 ? q : (which == 1 ? k : v);
    const unsigned short* WT = which == 0 ? wqT : (which == 1 ? wkT : wvT);
    const float* bias = which == 0 ? bq : (which == 1 ? bk : bv);
    unsigned short* Y = which == 0 ? qh : (which == 1 ? kh : vh);
    const bool phi = (which < 2);

    // XCD-chunked bijective swizzle (256 % 8 == 0)
    const int flat = blockIdx.x;
    const int wg = (flat & 7) * 32 + (flat >> 3);   // [0,256)
    const int m0 = wg * 128;
    const int wr = (w >> 2) * 64;       // wave m-offset (0 or 64)
    const int wc = (w & 3) * 128;       // wave n-offset (0..384)

    // A staging: thread t covers row t>>2 (0..127), 8 floats at col (t&3)*8
    const int arow = t >> 2;
    const int acol = (t & 3) * 8;
    const float* xp = X + (size_t)(m0 + arow) * DM + acol;

    // B staging (hoisted): slot j, thread t -> chunk c = j*512+t of [512 rows][4 chunks]
    const unsigned short* gbl[4];
    unsigned int lbo[4];
    #pragma unroll
    for (int j = 0; j < 4; ++j) {
        int c = j * 512 + t;
        int r = c >> 2, p = c & 3;
        int gd = p ^ (r & 3) ^ ((r >> 2) & 3);
        gbl[j] = WT + (size_t)r * DM + gd * 8;
        lbo[j] = c * 8;                 // linear position (wave-uniform base + lane*16B)
    }

    float bvx[8];
    #pragma unroll
    for (int n = 0; n < 8; ++n) bvx[n] = bias[wc + n * 16 + l15];

    floatx4 acc[4][8] = {};
    float4 avA0, avA1, avB0, avB1;      // two A-prefetch register sets (parity-static)

    #define STAGE_B(tile, buf)                                                  \
        _Pragma("unroll")                                                       \
        for (int j = 0; j < 4; ++j) gl_lds16(gbl[j] + (tile) * 32, &Bs[buf][lbo[j]]);

    #define WRITE_A_FROM(buf, r0, r1)                                           \
        *(uint4*)&As[buf][arow * 40 + acol] = make_uint4(                       \
            pack2_rtz(r0.x, r0.y), pack2_rtz(r0.z, r0.w),                       \
            pack2_rtz(r1.x, r1.y), pack2_rtz(r1.z, r1.w));

    #define FENCE() asm volatile("" ::: "memory")

    // prologue: B(0)+A(0) staged & drained; A(1) loads in flight (set B)
    STAGE_B(0, 0);
    avA0 = *(const float4*)xp; avA1 = *(const float4*)(xp + 4);
    asm volatile("s_waitcnt vmcnt(0)" ::: "memory");
    WRITE_A_FROM(0, avA0, avA1);
    avB0 = *(const float4*)(xp + 32); avB1 = *(const float4*)(xp + 36);

    #pragma unroll 2
    for (int tile = 0; tile < 16; ++tile) {
        const int cur = tile & 1, nxt = cur ^ 1;
        if (tile < 15) {
            asm volatile("s_waitcnt vmcnt(2)" ::: "memory");   // retire B(tile); A(tile+1) flies
        } else {
            asm volatile("s_waitcnt vmcnt(0)" ::: "memory");   // tail: retire B(15)
        }
        asm volatile("s_waitcnt lgkmcnt(0)" ::: "memory");     // A(tile) ds_write visible
        __builtin_amdgcn_s_barrier();        // bar-B: As[cur]+Bs[cur] ready block-wide
        FENCE();

        short8 af[4], bfr[8];
        // H1 loads + MFMA (n = 0..3)
        #pragma unroll
        for (int m = 0; m < 4; ++m)
            af[m] = *(const short8*)&As[cur][(wr + m * 16 + l15) * 40 + g * 8];
        #pragma unroll
        for (int n = 0; n < 4; ++n) {
            int r = wc + n * 16 + l15;
            int ch = g ^ (r & 3) ^ ((r >> 2) & 3);
            bfr[n] = *(const short8*)&Bs[cur][r * 32 + ch * 8];
        }
        __builtin_amdgcn_s_setprio(1);       // T5: favor MFMA-issuing wave
        #pragma unroll
        for (int m = 0; m < 4; ++m)
            #pragma unroll
            for (int n = 0; n < 4; ++n)
                acc[m][n] = __builtin_amdgcn_mfma_f32_16x16x32_bf16(af[m], bfr[n], acc[m][n], 0, 0, 0);
        __builtin_amdgcn_s_setprio(0);
        // finish all cur-reads (n = 4..7 fragments)
        #pragma unroll
        for (int n = 4; n < 8; ++n) {
            int r = wc + n * 16 + l15;
            int ch = g ^ (r & 3) ^ ((r >> 2) & 3);
            bfr[n] = *(const short8*)&Bs[cur][r * 32 + ch * 8];
        }
        // mid-compute staging: overlaps H1's MFMA drain; writes nxt buffers only
        if (tile < 15) {
            STAGE_B(tile + 1, nxt);                            // queue +4
            if (tile & 1) { WRITE_A_FROM(nxt, avA0, avA1); }   // A(tile+1) parity set
            else          { WRITE_A_FROM(nxt, avB0, avB1); }
            if (tile < 14) {                                   // LOAD_A(tile+2)
                const float* ap = xp + (tile + 2) * 32;
                if (tile & 1) { avB0 = *(const float4*)ap; avB1 = *(const float4*)(ap + 4); }
                else          { avA0 = *(const float4*)ap; avA1 = *(const float4*)(ap + 4); }
            }
        }
        // H2 MFMA (n = 4..7)
        __builtin_amdgcn_s_setprio(1);       // T5
        #pragma unroll
        for (int m = 0; m < 4; ++m)
            #pragma unroll
            for (int n = 4; n < 8; ++n)
                acc[m][n] = __builtin_amdgcn_mfma_f32_16x16x32_bf16(af[m], bfr[n], acc[m][n], 0, 0, 0);
        __builtin_amdgcn_s_setprio(0);

        __builtin_amdgcn_s_barrier();        // bar-A: all waves done reading [cur]
        FENCE();
    }

    // epilogue: C/D layout col=lane&15, row=(lane>>4)*4+reg  [verified m89/m91]
    #pragma unroll
    for (int n = 0; n < 8; ++n) {
        int col = wc + n * 16 + l15;
        float bb = bvx[n];
        #pragma unroll
        for (int m = 0; m < 4; ++m) {
            #pragma unroll
            for (int j = 0; j < 4; ++j) {
                int row = m0 + wr + m * 16 + g * 4 + j;
                float val = acc[m][n][j] + bb;
                if (phi) val = (val > 0.0f) ? (val + 1.0f) : __expf(val);  // elu(x)+1
                Y[(size_t)row * DM + col] = f2bf(val);
            }
        }
    }
    #undef STAGE_B
    #undef WRITE_A_FROM
    #undef FENCE
}

// ---- kv einsum + k_red via MFMA ----
// KV_CHUNK 1024: 256 blocks = 1/CU; atomics / 4 vs KV_CHUNK=256.
#define KV_CHUNK 1024
#define KV_TILE 32
__global__ __launch_bounds__(256) void kv_kernel(const unsigned short* __restrict__ kh,
                                                 const unsigned short* __restrict__ vh,
                                                 float* __restrict__ kv,
                                                 float* __restrict__ kred) {
    __shared__ unsigned short khT[64][40];
    __shared__ unsigned short vhT[64][40];

    const int t = threadIdx.x;
    const int w = t >> 6;
    const int l15 = t & 15;
    const int g = (t >> 4) & 3;
    const int b = blockIdx.z, h = blockIdx.y;
    const int s0 = blockIdx.x * KV_CHUNK;

    const int s_i = t >> 3;
    const int d0 = (t & 7) * 8;

    const size_t gbase = ((size_t)b * SEQ + s0 + s_i) * DM + h * DEPTH + d0;

    short8 ones;
    #pragma unroll
    for (int i = 0; i < 8; ++i) ones[i] = (short)0x3F80;  // bf16 1.0

    floatx4 acc[5] = {};

    int4 kr = *(const int4*)(kh + gbase);
    int4 vr = *(const int4*)(vh + gbase);

    #pragma unroll 4
    for (int tile = 0; tile < KV_CHUNK / KV_TILE; ++tile) {
        {
            const unsigned short* kk = (const unsigned short*)&kr;
            const unsigned short* vv = (const unsigned short*)&vr;
            #pragma unroll
            for (int i = 0; i < 8; ++i) khT[d0 + i][s_i] = kk[i];
            #pragma unroll
            for (int i = 0; i < 8; ++i) vhT[d0 + i][s_i] = vv[i];
        }
        if (tile + 1 < KV_CHUNK / KV_TILE) {
            size_t off = gbase + (size_t)(tile + 1) * KV_TILE * DM;
            kr = *(const int4*)(kh + off);
            vr = *(const int4*)(vh + off);
        }
        __syncthreads();

        short8 af = *(const short8*)&khT[w * 16 + l15][g * 8];
        short8 bf0 = *(const short8*)&vhT[0 * 16 + l15][g * 8];
        short8 bf1 = *(const short8*)&vhT[1 * 16 + l15][g * 8];
        short8 bf2 = *(const short8*)&vhT[2 * 16 + l15][g * 8];
        short8 bf3 = *(const short8*)&vhT[3 * 16 + l15][g * 8];
        acc[0] = __builtin_amdgcn_mfma_f32_16x16x32_bf16(af, bf0, acc[0], 0, 0, 0);
        acc[1] = __builtin_amdgcn_mfma_f32_16x16x32_bf16(af, bf1, acc[1], 0, 0, 0);
        acc[2] = __builtin_amdgcn_mfma_f32_16x16x32_bf16(af, bf2, acc[2], 0, 0, 0);
        acc[3] = __builtin_amdgcn_mfma_f32_16x16x32_bf16(af, ones, acc[3], 0, 0, 0);
        acc[4] = __builtin_amdgcn_mfma_f32_16x16x32_bf16(af, bf3, acc[4], 0, 0, 0);
        __syncthreads();
    }

    float* kvp = kv + (size_t)(b * HEADS + h) * (DEPTH * DEPTH);
    #pragma unroll
    for (int j = 0; j < 4; ++j) {
        int drow = w * 16 + g * 4 + j;
        atomicAdd(&kvp[drow * DEPTH + 0 * 16 + l15], acc[0][j]);
        atomicAdd(&kvp[drow * DEPTH + 1 * 16 + l15], acc[1][j]);
        atomicAdd(&kvp[drow * DEPTH + 2 * 16 + l15], acc[2][j]);
        atomicAdd(&kvp[drow * DEPTH + 3 * 16 + l15], acc[4][j]);
    }
    if (l15 == 0) {
        float* krp = kred + (b * HEADS + h) * DEPTH;
        #pragma unroll
        for (int j = 0; j < 4; ++j)
            atomicAdd(&krp[w * 16 + g * 4 + j], acc[3][j]);
    }
}

// ---- out via MFMA: per (b,h): out[s][e] = (qh[s][:] @ KV[:][e]) / (qh[s][:] @ (kred+eps)) ----
__global__ __launch_bounds__(256) void out_kernel(const unsigned short* __restrict__ qh,
                                                  const float* __restrict__ kv,
                                                  const float* __restrict__ kred,
                                                  float* __restrict__ out) {
    __shared__ unsigned short Qs[256 * 64];    // 32 KiB, chunk-XOR swizzled (&7)
    __shared__ unsigned short KVTs[80][72];    // pad-72 (2-way alias = free)

    const int t = threadIdx.x;
    const int l = t & 63;
    const int w = t >> 6;
    const int l15 = l & 15;
    const int g = l >> 4;
    const int b = blockIdx.z, h = blockIdx.y;
    const int s0 = blockIdx.x * 256;
    const int wr = w * 64;

    const size_t qbase = ((size_t)b * SEQ + s0) * DM + h * DEPTH;
    #pragma unroll
    for (int i = 0; i < 8; ++i) {
        int c = i * 256 + t;
        int r = c >> 3;
        int gp = c & 7;
        int gd = gp ^ (r & 7);
        const unsigned short* gsrc = qh + qbase + (size_t)r * DM + gd * 8;
        unsigned short* ldst = Qs + ((size_t)i * 256 + w * 64) * 8;
        gl_lds16(gsrc, ldst);
    }

    const float* kvp = kv + (size_t)(b * HEADS + h) * (DEPTH * DEPTH);
    const float* krp = kred + (size_t)(b * HEADS + h) * DEPTH;
    #pragma unroll
    for (int j = 0; j < 20; ++j) {
        int f = j * 256 + t;
        int e = f >> 6, d = f & 63;
        float val = (e < 64) ? kvp[d * DEPTH + e]
                  : (e == 64 ? (krp[d] + 1e-8f) : 0.0f);
        KVTs[e][d] = f2bf(val);
    }

    __syncthreads();

    short8 af[2][4], bfr[2][5];
    #pragma unroll
    for (int kk = 0; kk < 2; ++kk) {
        #pragma unroll
        for (int m = 0; m < 4; ++m) {
            int r = wr + m * 16 + l15;
            int ch = (kk * 4 + g) ^ (r & 7);
            af[kk][m] = *(const short8*)(Qs + r * 64 + ch * 8);
        }
        #pragma unroll
        for (int n = 0; n < 5; ++n)
            bfr[kk][n] = *(const short8*)&KVTs[n * 16 + l15][kk * 32 + g * 8];
    }

    floatx4 acc[4][5] = {};
    #pragma unroll
    for (int kk = 0; kk < 2; ++kk)
        #pragma unroll
        for (int m = 0; m < 4; ++m)
            #pragma unroll
            for (int n = 0; n < 5; ++n)
                acc[m][n] = __builtin_amdgcn_mfma_f32_16x16x32_bf16(af[kk][m], bfr[kk][n], acc[m][n], 0, 0, 0);

    float* op = out + ((size_t)b * SEQ + s0) * DM + h * DEPTH;
    #pragma unroll
    for (int m = 0; m < 4; ++m) {
        #pragma unroll
        for (int j = 0; j < 4; ++j) {
            float den = __shfl(acc[m][4][j], l & 48);
            float z = 1.0f / den;
            int row = wr + m * 16 + g * 4 + j;
            #pragma unroll
            for (int n = 0; n < 4; ++n)
                op[(size_t)row * DM + n * 16 + l15] = acc[m][n][j] * z;
        }
    }
}

extern "C" void kernel_launch(void* const* d_in, const int* in_sizes, int n_in,
                              void* d_out, int out_size, void* d_ws, size_t ws_size,
                              hipStream_t stream) {
    const float* q  = (const float*)d_in[0];
    const float* k  = (const float*)d_in[1];
    const float* v  = (const float*)d_in[2];
    const float* wq = (const float*)d_in[3];
    const float* bq = (const float*)d_in[4];
    const float* wk = (const float*)d_in[5];
    const float* bk = (const float*)d_in[6];
    const float* wv = (const float*)d_in[7];
    const float* bv = (const float*)d_in[8];
    float* out = (float*)d_out;

    char* ws = (char*)d_ws;
    const size_t sz_h = (size_t)MROWS * DM * 2;                 // 32 MiB each (bf16)
    unsigned short* qh  = (unsigned short*)(ws);
    unsigned short* kh  = (unsigned short*)(ws + sz_h);
    unsigned short* vh  = (unsigned short*)(ws + 2 * sz_h);
    unsigned short* wqT = (unsigned short*)(ws + 3 * sz_h);
    unsigned short* wkT = wqT + DM * DM;
    unsigned short* wvT = wkT + DM * DM;
    float* kvbuf   = (float*)(ws + 3 * sz_h + (size_t)3 * DM * DM * 2);
    float* kredbuf = kvbuf + BATCH * HEADS * DEPTH * DEPTH;

    hipMemsetAsync(kvbuf, 0,
                   (size_t)(BATCH * HEADS * DEPTH * DEPTH + BATCH * HEADS * DEPTH) * sizeof(float),
                   stream);

    wprep_kernel<<<dim3(DM * DM / 256, 3), 256, 0, stream>>>(wq, wk, wv, wqT, wkT, wvT);

    // merged dispatch: 256 blocks (BM=128, BN=512 single n-panel) x 3 inputs
    proj3_kernel<<<dim3(256, 3), 512, 0, stream>>>(q, k, v, wqT, wkT, wvT,
                                                   bq, bk, bv, qh, kh, vh);

    kv_kernel<<<dim3(SEQ / KV_CHUNK, HEADS, BATCH), 256, 0, stream>>>(kh, vh, kvbuf, kredbuf);
    out_kernel<<<dim3(SEQ / 256, HEADS, BATCH), 256, 0, stream>>>(qh, kvbuf, kredbuf, out);
}

// Round 23
// 152.820 us; speedup vs baseline: 1.0090x; 1.0090x over previous
//
#include <hip/hip_runtime.h>
#include <hip/hip_bf16.h>

#define DM 512
#define HEADS 8
#define DEPTH 64
#define BATCH 4
#define SEQ 8192
#define MROWS (BATCH*SEQ)

using short8 = __attribute__((ext_vector_type(8))) short;
using floatx4 = __attribute__((ext_vector_type(4))) float;

#define AS1 __attribute__((address_space(1)))
#define AS3 __attribute__((address_space(3)))

static __device__ __forceinline__ float bf2f(unsigned short u) {
    union { unsigned int i; float f; } x; x.i = ((unsigned int)u) << 16; return x.f;
}
static __device__ __forceinline__ unsigned short f2bf(float f) {
    union { float f; unsigned int i; } x; x.f = f;
    unsigned int i = x.i;
    return (unsigned short)((i + 0x7FFFu + ((i >> 16) & 1u)) >> 16);
}
// RTZ pack: 3 VALU ops (A-staging only)
static __device__ __forceinline__ unsigned int pack2_rtz(float a, float b) {
    union { float f; unsigned int u; } x, y; x.f = a; y.f = b;
    return (x.u >> 16) | (y.u & 0xFFFF0000u);
}
static __device__ __forceinline__ void gl_lds16(const unsigned short* g, unsigned short* l) {
    __builtin_amdgcn_global_load_lds((const AS1 unsigned int*)g, (AS3 unsigned int*)l, 16, 0, 0);
}

// ---- W prep (merged): transpose + convert to bf16. wT[n][k] = w[k][n] ----
__global__ __launch_bounds__(256) void wprep_kernel(const float* __restrict__ wq,
                                                    const float* __restrict__ wk,
                                                    const float* __restrict__ wv,
                                                    unsigned short* __restrict__ wqT,
                                                    unsigned short* __restrict__ wkT,
                                                    unsigned short* __restrict__ wvT) {
    const float* w = blockIdx.y == 0 ? wq : (blockIdx.y == 1 ? wk : wv);
    unsigned short* wT = blockIdx.y == 0 ? wqT : (blockIdx.y == 1 ? wkT : wvT);
    int idx = blockIdx.x * 256 + threadIdx.x;
    int k = idx & (DM - 1);
    int n = idx >> 9;
    wT[n * DM + k] = f2bf(w[k * DM + n]);
}

// ---- Merged projection GEMM: Y = phi?(X @ W + bias), q/k/v in one dispatch ----
// FINAL (R21 — session best: 153.1us total). MID-COMPUTE STAGING on the R16
// optimum: per iter {vmcnt(2); lgkm(0); bar-B; H1 (af+bfr[0..3] loads, 16 MFMA);
// bfr[4..7] loads (all cur-reads complete); STAGE_B(t+1)+WRITE_A(t+1)+LOAD_A(t+2)
// (nxt buffers only — safe: after prev iter's bar-A via this bar-B); H2 (16 MFMA);
// bar-A}. Staging issues while H1's MFMAs drain the matrix pipe.
// Ledger (induction-checked): entering iter t: [B(t)x4, A(t+1)x2] -> vmcnt(2)
// retires exactly B(t)x4; t=0 no-op (B(0) drained pre-loop); t=15 vmcnt(0).
// Geometry: BM=128/BN=512/BK=32, 8 waves (2m x 4n), acc 4x8, chunk-XOR B
// (s(r)=(r&3)^((r>>2)&3)), pad-40 A, LDS 84KB. 10 A/B'd variants (tile shapes,
// buffer depths, drain placements, direct-L2 B, setprio) all regress 1-45%.
__global__ __launch_bounds__(512) void proj3_kernel(
        const float* __restrict__ q, const float* __restrict__ k, const float* __restrict__ v,
        const unsigned short* __restrict__ wqT, const unsigned short* __restrict__ wkT,
        const unsigned short* __restrict__ wvT,
        const float* __restrict__ bq, const float* __restrict__ bk, const float* __restrict__ bv,
        unsigned short* __restrict__ qh, unsigned short* __restrict__ kh,
        unsigned short* __restrict__ vh) {
    __shared__ unsigned short As[2][128 * 40];   // 2 x 10 KiB (80B rows)
    __shared__ unsigned short Bs[2][512 * 32];   // 2 x 32 KiB (chunk-XOR contents)

    const int t = threadIdx.x;
    const int w = t >> 6;
    const int l15 = t & 15;
    const int g = (t >> 4) & 3;

    const int which = blockIdx.y;
    const float* X = which == 0 ? q : (which == 1 ? k : v);
    const unsigned short* WT = which == 0 ? wqT : (which == 1 ? wkT : wvT);
    const float* bias = which == 0 ? bq : (which == 1 ? bk : bv);
    unsigned short* Y = which == 0 ? qh : (which == 1 ? kh : vh);
    const bool phi = (which < 2);

    // XCD-chunked bijective swizzle (256 % 8 == 0)
    const int flat = blockIdx.x;
    const int wg = (flat & 7) * 32 + (flat >> 3);   // [0,256)
    const int m0 = wg * 128;
    const int wr = (w >> 2) * 64;       // wave m-offset (0 or 64)
    const int wc = (w & 3) * 128;       // wave n-offset (0..384)

    // A staging: thread t covers row t>>2 (0..127), 8 floats at col (t&3)*8
    const int arow = t >> 2;
    const int acol = (t & 3) * 8;
    const float* xp = X + (size_t)(m0 + arow) * DM + acol;

    // B staging (hoisted): slot j, thread t -> chunk c = j*512+t of [512 rows][4 chunks]
    const unsigned short* gbl[4];
    unsigned int lbo[4];
    #pragma unroll
    for (int j = 0; j < 4; ++j) {
        int c = j * 512 + t;
        int r = c >> 2, p = c & 3;
        int gd = p ^ (r & 3) ^ ((r >> 2) & 3);
        gbl[j] = WT + (size_t)r * DM + gd * 8;
        lbo[j] = c * 8;                 // linear position (wave-uniform base + lane*16B)
    }

    float bvx[8];
    #pragma unroll
    for (int n = 0; n < 8; ++n) bvx[n] = bias[wc + n * 16 + l15];

    floatx4 acc[4][8] = {};
    float4 avA0, avA1, avB0, avB1;      // two A-prefetch register sets (parity-static)

    #define STAGE_B(tile, buf)                                                  \
        _Pragma("unroll")                                                       \
        for (int j = 0; j < 4; ++j) gl_lds16(gbl[j] + (tile) * 32, &Bs[buf][lbo[j]]);

    #define WRITE_A_FROM(buf, r0, r1)                                           \
        *(uint4*)&As[buf][arow * 40 + acol] = make_uint4(                       \
            pack2_rtz(r0.x, r0.y), pack2_rtz(r0.z, r0.w),                       \
            pack2_rtz(r1.x, r1.y), pack2_rtz(r1.z, r1.w));

    #define FENCE() asm volatile("" ::: "memory")

    // prologue: B(0)+A(0) staged & drained; A(1) loads in flight (set B)
    STAGE_B(0, 0);
    avA0 = *(const float4*)xp; avA1 = *(const float4*)(xp + 4);
    asm volatile("s_waitcnt vmcnt(0)" ::: "memory");
    WRITE_A_FROM(0, avA0, avA1);
    avB0 = *(const float4*)(xp + 32); avB1 = *(const float4*)(xp + 36);

    #pragma unroll 2
    for (int tile = 0; tile < 16; ++tile) {
        const int cur = tile & 1, nxt = cur ^ 1;
        if (tile < 15) {
            asm volatile("s_waitcnt vmcnt(2)" ::: "memory");   // retire B(tile); A(tile+1) flies
        } else {
            asm volatile("s_waitcnt vmcnt(0)" ::: "memory");   // tail: retire B(15)
        }
        asm volatile("s_waitcnt lgkmcnt(0)" ::: "memory");     // A(tile) ds_write visible
        __builtin_amdgcn_s_barrier();        // bar-B: As[cur]+Bs[cur] ready block-wide
        FENCE();

        short8 af[4], bfr[8];
        // H1 loads + MFMA (n = 0..3)
        #pragma unroll
        for (int m = 0; m < 4; ++m)
            af[m] = *(const short8*)&As[cur][(wr + m * 16 + l15) * 40 + g * 8];
        #pragma unroll
        for (int n = 0; n < 4; ++n) {
            int r = wc + n * 16 + l15;
            int ch = g ^ (r & 3) ^ ((r >> 2) & 3);
            bfr[n] = *(const short8*)&Bs[cur][r * 32 + ch * 8];
        }
        #pragma unroll
        for (int m = 0; m < 4; ++m)
            #pragma unroll
            for (int n = 0; n < 4; ++n)
                acc[m][n] = __builtin_amdgcn_mfma_f32_16x16x32_bf16(af[m], bfr[n], acc[m][n], 0, 0, 0);
        // finish all cur-reads (n = 4..7 fragments)
        #pragma unroll
        for (int n = 4; n < 8; ++n) {
            int r = wc + n * 16 + l15;
            int ch = g ^ (r & 3) ^ ((r >> 2) & 3);
            bfr[n] = *(const short8*)&Bs[cur][r * 32 + ch * 8];
        }
        // mid-compute staging: overlaps H1's MFMA drain; writes nxt buffers only
        if (tile < 15) {
            STAGE_B(tile + 1, nxt);                            // queue +4
            if (tile & 1) { WRITE_A_FROM(nxt, avA0, avA1); }   // A(tile+1) parity set
            else          { WRITE_A_FROM(nxt, avB0, avB1); }
            if (tile < 14) {                                   // LOAD_A(tile+2)
                const float* ap = xp + (tile + 2) * 32;
                if (tile & 1) { avB0 = *(const float4*)ap; avB1 = *(const float4*)(ap + 4); }
                else          { avA0 = *(const float4*)ap; avA1 = *(const float4*)(ap + 4); }
            }
        }
        // H2 MFMA (n = 4..7)
        #pragma unroll
        for (int m = 0; m < 4; ++m)
            #pragma unroll
            for (int n = 4; n < 8; ++n)
                acc[m][n] = __builtin_amdgcn_mfma_f32_16x16x32_bf16(af[m], bfr[n], acc[m][n], 0, 0, 0);

        __builtin_amdgcn_s_barrier();        // bar-A: all waves done reading [cur]
        FENCE();
    }

    // epilogue: C/D layout col=lane&15, row=(lane>>4)*4+reg  [verified m89/m91]
    #pragma unroll
    for (int n = 0; n < 8; ++n) {
        int col = wc + n * 16 + l15;
        float bb = bvx[n];
        #pragma unroll
        for (int m = 0; m < 4; ++m) {
            #pragma unroll
            for (int j = 0; j < 4; ++j) {
                int row = m0 + wr + m * 16 + g * 4 + j;
                float val = acc[m][n][j] + bb;
                if (phi) val = (val > 0.0f) ? (val + 1.0f) : __expf(val);  // elu(x)+1
                Y[(size_t)row * DM + col] = f2bf(val);
            }
        }
    }
    #undef STAGE_B
    #undef WRITE_A_FROM
    #undef FENCE
}

// ---- kv einsum + k_red via MFMA ----
// KV_CHUNK 1024: 256 blocks = 1/CU; atomics / 4 vs KV_CHUNK=256.
#define KV_CHUNK 1024
#define KV_TILE 32
__global__ __launch_bounds__(256) void kv_kernel(const unsigned short* __restrict__ kh,
                                                 const unsigned short* __restrict__ vh,
                                                 float* __restrict__ kv,
                                                 float* __restrict__ kred) {
    __shared__ unsigned short khT[64][40];
    __shared__ unsigned short vhT[64][40];

    const int t = threadIdx.x;
    const int w = t >> 6;
    const int l15 = t & 15;
    const int g = (t >> 4) & 3;
    const int b = blockIdx.z, h = blockIdx.y;
    const int s0 = blockIdx.x * KV_CHUNK;

    const int s_i = t >> 3;
    const int d0 = (t & 7) * 8;

    const size_t gbase = ((size_t)b * SEQ + s0 + s_i) * DM + h * DEPTH + d0;

    short8 ones;
    #pragma unroll
    for (int i = 0; i < 8; ++i) ones[i] = (short)0x3F80;  // bf16 1.0

    floatx4 acc[5] = {};

    int4 kr = *(const int4*)(kh + gbase);
    int4 vr = *(const int4*)(vh + gbase);

    #pragma unroll 4
    for (int tile = 0; tile < KV_CHUNK / KV_TILE; ++tile) {
        {
            const unsigned short* kk = (const unsigned short*)&kr;
            const unsigned short* vv = (const unsigned short*)&vr;
            #pragma unroll
            for (int i = 0; i < 8; ++i) khT[d0 + i][s_i] = kk[i];
            #pragma unroll
            for (int i = 0; i < 8; ++i) vhT[d0 + i][s_i] = vv[i];
        }
        if (tile + 1 < KV_CHUNK / KV_TILE) {
            size_t off = gbase + (size_t)(tile + 1) * KV_TILE * DM;
            kr = *(const int4*)(kh + off);
            vr = *(const int4*)(vh + off);
        }
        __syncthreads();

        short8 af = *(const short8*)&khT[w * 16 + l15][g * 8];
        short8 bf0 = *(const short8*)&vhT[0 * 16 + l15][g * 8];
        short8 bf1 = *(const short8*)&vhT[1 * 16 + l15][g * 8];
        short8 bf2 = *(const short8*)&vhT[2 * 16 + l15][g * 8];
        short8 bf3 = *(const short8*)&vhT[3 * 16 + l15][g * 8];
        acc[0] = __builtin_amdgcn_mfma_f32_16x16x32_bf16(af, bf0, acc[0], 0, 0, 0);
        acc[1] = __builtin_amdgcn_mfma_f32_16x16x32_bf16(af, bf1, acc[1], 0, 0, 0);
        acc[2] = __builtin_amdgcn_mfma_f32_16x16x32_bf16(af, bf2, acc[2], 0, 0, 0);
        acc[3] = __builtin_amdgcn_mfma_f32_16x16x32_bf16(af, ones, acc[3], 0, 0, 0);
        acc[4] = __builtin_amdgcn_mfma_f32_16x16x32_bf16(af, bf3, acc[4], 0, 0, 0);
        __syncthreads();
    }

    float* kvp = kv + (size_t)(b * HEADS + h) * (DEPTH * DEPTH);
    #pragma unroll
    for (int j = 0; j < 4; ++j) {
        int drow = w * 16 + g * 4 + j;
        atomicAdd(&kvp[drow * DEPTH + 0 * 16 + l15], acc[0][j]);
        atomicAdd(&kvp[drow * DEPTH + 1 * 16 + l15], acc[1][j]);
        atomicAdd(&kvp[drow * DEPTH + 2 * 16 + l15], acc[2][j]);
        atomicAdd(&kvp[drow * DEPTH + 3 * 16 + l15], acc[4][j]);
    }
    if (l15 == 0) {
        float* krp = kred + (b * HEADS + h) * DEPTH;
        #pragma unroll
        for (int j = 0; j < 4; ++j)
            atomicAdd(&krp[w * 16 + g * 4 + j], acc[3][j]);
    }
}

// ---- out via MFMA: per (b,h): out[s][e] = (qh[s][:] @ KV[:][e]) / (qh[s][:] @ (kred+eps)) ----
__global__ __launch_bounds__(256) void out_kernel(const unsigned short* __restrict__ qh,
                                                  const float* __restrict__ kv,
                                                  const float* __restrict__ kred,
                                                  float* __restrict__ out) {
    __shared__ unsigned short Qs[256 * 64];    // 32 KiB, chunk-XOR swizzled (&7)
    __shared__ unsigned short KVTs[80][72];    // pad-72 (2-way alias = free)

    const int t = threadIdx.x;
    const int l = t & 63;
    const int w = t >> 6;
    const int l15 = l & 15;
    const int g = l >> 4;
    const int b = blockIdx.z, h = blockIdx.y;
    const int s0 = blockIdx.x * 256;
    const int wr = w * 64;

    const size_t qbase = ((size_t)b * SEQ + s0) * DM + h * DEPTH;
    #pragma unroll
    for (int i = 0; i < 8; ++i) {
        int c = i * 256 + t;
        int r = c >> 3;
        int gp = c & 7;
        int gd = gp ^ (r & 7);
        const unsigned short* gsrc = qh + qbase + (size_t)r * DM + gd * 8;
        unsigned short* ldst = Qs + ((size_t)i * 256 + w * 64) * 8;
        gl_lds16(gsrc, ldst);
    }

    const float* kvp = kv + (size_t)(b * HEADS + h) * (DEPTH * DEPTH);
    const float* krp = kred + (size_t)(b * HEADS + h) * DEPTH;
    #pragma unroll
    for (int j = 0; j < 20; ++j) {
        int f = j * 256 + t;
        int e = f >> 6, d = f & 63;
        float val = (e < 64) ? kvp[d * DEPTH + e]
                  : (e == 64 ? (krp[d] + 1e-8f) : 0.0f);
        KVTs[e][d] = f2bf(val);
    }

    __syncthreads();

    short8 af[2][4], bfr[2][5];
    #pragma unroll
    for (int kk = 0; kk < 2; ++kk) {
        #pragma unroll
        for (int m = 0; m < 4; ++m) {
            int r = wr + m * 16 + l15;
            int ch = (kk * 4 + g) ^ (r & 7);
            af[kk][m] = *(const short8*)(Qs + r * 64 + ch * 8);
        }
        #pragma unroll
        for (int n = 0; n < 5; ++n)
            bfr[kk][n] = *(const short8*)&KVTs[n * 16 + l15][kk * 32 + g * 8];
    }

    floatx4 acc[4][5] = {};
    #pragma unroll
    for (int kk = 0; kk < 2; ++kk)
        #pragma unroll
        for (int m = 0; m < 4; ++m)
            #pragma unroll
            for (int n = 0; n < 5; ++n)
                acc[m][n] = __builtin_amdgcn_mfma_f32_16x16x32_bf16(af[kk][m], bfr[kk][n], acc[m][n], 0, 0, 0);

    float* op = out + ((size_t)b * SEQ + s0) * DM + h * DEPTH;
    #pragma unroll
    for (int m = 0; m < 4; ++m) {
        #pragma unroll
        for (int j = 0; j < 4; ++j) {
            float den = __shfl(acc[m][4][j], l & 48);
            float z = 1.0f / den;
            int row = wr + m * 16 + g * 4 + j;
            #pragma unroll
            for (int n = 0; n < 4; ++n)
                op[(size_t)row * DM + n * 16 + l15] = acc[m][n][j] * z;
        }
    }
}

extern "C" void kernel_launch(void* const* d_in, const int* in_sizes, int n_in,
                              void* d_out, int out_size, void* d_ws, size_t ws_size,
                              hipStream_t stream) {
    const float* q  = (const float*)d_in[0];
    const float* k  = (const float*)d_in[1];
    const float* v  = (const float*)d_in[2];
    const float* wq = (const float*)d_in[3];
    const float* bq = (const float*)d_in[4];
    const float* wk = (const float*)d_in[5];
    const float* bk = (const float*)d_in[6];
    const float* wv = (const float*)d_in[7];
    const float* bv = (const float*)d_in[8];
    float* out = (float*)d_out;

    char* ws = (char*)d_ws;
    const size_t sz_h = (size_t)MROWS * DM * 2;                 // 32 MiB each (bf16)
    unsigned short* qh  = (unsigned short*)(ws);
    unsigned short* kh  = (unsigned short*)(ws + sz_h);
    unsigned short* vh  = (unsigned short*)(ws + 2 * sz_h);
    unsigned short* wqT = (unsigned short*)(ws + 3 * sz_h);
    unsigned short* wkT = wqT + DM * DM;
    unsigned short* wvT = wkT + DM * DM;
    float* kvbuf   = (float*)(ws + 3 * sz_h + (size_t)3 * DM * DM * 2);
    float* kredbuf = kvbuf + BATCH * HEADS * DEPTH * DEPTH;

    hipMemsetAsync(kvbuf, 0,
                   (size_t)(BATCH * HEADS * DEPTH * DEPTH + BATCH * HEADS * DEPTH) * sizeof(float),
                   stream);

    wprep_kernel<<<dim3(DM * DM / 256, 3), 256, 0, stream>>>(wq, wk, wv, wqT, wkT, wvT);

    // merged dispatch: 256 blocks (BM=128, BN=512 single n-panel) x 3 inputs
    proj3_kernel<<<dim3(256, 3), 512, 0, stream>>>(q, k, v, wqT, wkT, wvT,
                                                   bq, bk, bv, qh, kh, vh);

    kv_kernel<<<dim3(SEQ / KV_CHUNK, HEADS, BATCH), 256, 0, stream>>>(kh, vh, kvbuf, kredbuf);
    out_kernel<<<dim3(SEQ / 256, HEADS, BATCH), 256, 0, stream>>>(qh, kvbuf, kredbuf, out);
}